// Round 2
// baseline (357.882 us; speedup 1.0000x reference)
//
#include <hip/hip_runtime.h>
#include <stdint.h>

// MultiHeadAttentionProj: B=4, N=2048, D=512, H=8, HD=64
// Pipeline: cvt(f32->bf16) -> GEMM QKV (bf16 MFMA) -> flash attention -> GEMM out
// All bf16 stored as raw short bits; fp32 accumulation everywhere.

typedef __attribute__((ext_vector_type(8))) short short8;   // 8 bf16 = one MFMA A/B frag
typedef __attribute__((ext_vector_type(4))) short short4v;
typedef __attribute__((ext_vector_type(4))) float f32x4;    // MFMA C/D frag

#define DEV static __device__ __forceinline__

constexpr int Bc = 4, Nc = 2048, Dc = 512, Hc = 8, HDc = 64;
constexpr int Mc = Bc * Nc;        // 8192 rows
constexpr int QKVNc = 3 * Dc;      // 1536 (Q|K|V concatenated columns)

DEV unsigned short f2bits(float f) {   // f32 -> bf16 bits, round-to-nearest-even
  union { float f; unsigned u; } a; a.f = f;
  unsigned r = a.u + 0x7fffu + ((a.u >> 16) & 1u);
  return (unsigned short)(r >> 16);
}

__global__ void cvt_kernel(const float* __restrict__ src, short* __restrict__ dst, int n4) {
  int i = blockIdx.x * blockDim.x + threadIdx.x;
  if (i >= n4) return;
  float4 v = ((const float4*)src)[i];
  short4v o = { (short)f2bits(v.x), (short)f2bits(v.y), (short)f2bits(v.z), (short)f2bits(v.w) };
  ((short4v*)dst)[i] = o;
}

// mask may arrive as int32 (4B) or as raw bool bytes (1B). Detect on-device:
// int32 0/1 little-endian has bytes 1..3 of every word == 0; random bools don't.
__global__ void detect_kernel(const uchar4* __restrict__ m, int* __restrict__ flag) {
  __shared__ int s;
  if (threadIdx.x == 0) s = 0;
  __syncthreads();
  int acc = 0;
  for (int i = threadIdx.x; i < (Bc * Nc) / 4; i += 256) {
    uchar4 v = m[i];
    acc |= (int)v.y | (int)v.z | (int)v.w;
  }
  if (acc) atomicOr(&s, 1);
  __syncthreads();
  if (threadIdx.x == 0) *flag = s;
}

__global__ void mask_kernel(const void* __restrict__ mask, const int* __restrict__ flag,
                            float* __restrict__ mf, int n) {
  int i = blockIdx.x * blockDim.x + threadIdx.x;
  if (i >= n) return;
  int isbyte = *flag;
  int v = isbyte ? (int)((const unsigned char*)mask)[i] : ((const int*)mask)[i];
  mf[i] = v ? -1e30f : 0.0f;   // additive key mask
}

// C[M][N] = sum_k A[m][k] * Bm[n][k]  (both K-contiguous, "BT" GEMM)
// 128x128 block tile, 4 waves in 2x2, each wave 4x4 x (16x16) MFMA tiles, BK=64.
template<bool OUT_F32>
__global__ __launch_bounds__(256) void gemm_bt(const short* __restrict__ A,
                                               const short* __restrict__ Bm,
                                               void* __restrict__ Cv,
                                               int M, int N, int K) {
  __shared__ __align__(16) short At[128 * 64];
  __shared__ __align__(16) short Bt[128 * 64];
  const int tid = threadIdx.x, lane = tid & 63, wv = tid >> 6;
  const int quad = lane >> 4, l16 = lane & 15;
  const int mbase = blockIdx.y * 128, nbase = blockIdx.x * 128;
  const int wr = (wv >> 1) * 64, wc = (wv & 1) * 64;
  f32x4 acc[4][4] = {};
  for (int k0 = 0; k0 < K; k0 += 64) {
    __syncthreads();
#pragma unroll
    for (int i = 0; i < 4; i++) {                 // stage 128x64 bf16 tiles (16 KB each)
      int flat = i * 256 + tid;                   // 0..1023 16B-chunks, 8 chunks/row
      int row = flat >> 3, ch = (flat & 7) * 8;
      *(short8*)&At[flat * 8] = *(const short8*)&A[(size_t)(mbase + row) * K + k0 + ch];
      *(short8*)&Bt[flat * 8] = *(const short8*)&Bm[(size_t)(nbase + row) * K + k0 + ch];
    }
    __syncthreads();
#pragma unroll
    for (int s = 0; s < 2; s++) {                 // two K=32 MFMA steps
      short8 af[4], bf[4];
#pragma unroll
      for (int t = 0; t < 4; t++) {
        af[t] = *(short8*)&At[(wr + t * 16 + l16) * 64 + quad * 8 + s * 32];
        bf[t] = *(short8*)&Bt[(wc + t * 16 + l16) * 64 + quad * 8 + s * 32];
      }
#pragma unroll
      for (int mt = 0; mt < 4; mt++)
#pragma unroll
        for (int nt = 0; nt < 4; nt++)
          acc[mt][nt] = __builtin_amdgcn_mfma_f32_16x16x32_bf16(af[mt], bf[nt], acc[mt][nt], 0, 0, 0);
    }
  }
#pragma unroll
  for (int mt = 0; mt < 4; mt++)
#pragma unroll
    for (int nt = 0; nt < 4; nt++)
#pragma unroll
      for (int r = 0; r < 4; r++) {               // C/D layout: row=quad*4+r, col=l16
        int row = mbase + wr + mt * 16 + quad * 4 + r;
        int col = nbase + wc + nt * 16 + l16;
        if (OUT_F32) ((float*)Cv)[(size_t)row * N + col] = acc[mt][nt][r];
        else         ((short*)Cv)[(size_t)row * N + col] = (short)f2bits(acc[mt][nt][r]);
      }
}

// Flash attention. Block = (b, h, 64-row q-tile); 4 waves x 16 q-rows each.
// Iterate 32 key-tiles of 64: S=QK^T/8+bias+mask -> online softmax -> O += P*V.
__global__ __launch_bounds__(256) void attn_kernel(const short* __restrict__ QKV,
                                                   const float* __restrict__ bias,
                                                   const float* __restrict__ maskf,
                                                   short* __restrict__ Aout) {
  __shared__ __align__(16) short Kt[64 * 64];        // [key][hd]
  __shared__ __align__(16) short Vt[64 * 64];        // transposed: [hd][key]
  __shared__ __align__(16) short Pt[4][16 * 64];     // per-wave P round-trip
  const int tid = threadIdx.x, lane = tid & 63, wv = tid >> 6;
  const int quad = lane >> 4, l16 = lane & 15;
  const int qt = blockIdx.x & 31, h = (blockIdx.x >> 5) & 7, b = (int)(blockIdx.x >> 8);
  const int qrow0 = qt * 64;
  const float* biasb = bias + (size_t)b * Nc * Nc;
  const float* mfb = maskf + b * Nc;

  short8 qf[2];  // Q A-frags for this wave's 16 rows (m=l16, k=quad*8+j+s*32)
  {
    const short* qp = QKV + (size_t)(b * Nc + qrow0 + wv * 16 + l16) * QKVNc + h * HDc + quad * 8;
    qf[0] = *(const short8*)qp;
    qf[1] = *(const short8*)(qp + 32);
  }
  f32x4 oacc[4] = {};
  float mrow[4], lrow[4];
#pragma unroll
  for (int r = 0; r < 4; r++) { mrow[r] = -1e30f; lrow[r] = 0.f; }

  for (int kt = 0; kt < 32; kt++) {
    const int kb = kt * 64;
    __syncthreads();                                  // prev iter's K/V reads done
#pragma unroll
    for (int i = 0; i < 2; i++) {                     // stage K tile row-major: 64 keys x 64 hd
      int flat = i * 256 + tid;                       // 512 chunks, 8 chunks/row
      int krow = flat >> 3, ch = (flat & 7) * 8;
      *(short8*)&Kt[flat * 8] =
          *(const short8*)&QKV[(size_t)(b * Nc + kb + krow) * QKVNc + Dc + h * HDc + ch];
    }
#pragma unroll
    for (int i = 0; i < 2; i++) {                     // stage V transposed -> [hd][key]
      int flat = i * 256 + tid;
      int hd0 = (flat >> 6) * 8, key = flat & 63;
      short8 v = *(const short8*)&QKV[(size_t)(b * Nc + kb + key) * QKVNc + 2 * Dc + h * HDc + hd0];
#pragma unroll
      for (int j = 0; j < 8; j++) Vt[(hd0 + j) * 64 + key] = v[j];
    }
    __syncthreads();

    f32x4 sacc[4] = {};
#pragma unroll
    for (int s = 0; s < 2; s++)
#pragma unroll
      for (int t = 0; t < 4; t++) {                   // S[q][key]: B-frag n = key row
        short8 kf = *(short8*)&Kt[(t * 16 + l16) * 64 + quad * 8 + s * 32];
        sacc[t] = __builtin_amdgcn_mfma_f32_16x16x32_bf16(qf[s], kf, sacc[t], 0, 0, 0);
      }

    float sval[4][4];
#pragma unroll
    for (int t = 0; t < 4; t++) {
      int col = kb + t * 16 + l16;
      float mk = mfb[col];
#pragma unroll
      for (int r = 0; r < 4; r++) {
        int qi = qrow0 + wv * 16 + quad * 4 + r;
        sval[t][r] = sacc[t][r] * 0.125f + biasb[(size_t)qi * Nc + col] + mk;
      }
    }
#pragma unroll
    for (int r = 0; r < 4; r++) {                     // online softmax per q-row
      float vm = fmaxf(fmaxf(sval[0][r], sval[1][r]), fmaxf(sval[2][r], sval[3][r]));
      vm = fmaxf(vm, __shfl_xor(vm, 1));
      vm = fmaxf(vm, __shfl_xor(vm, 2));
      vm = fmaxf(vm, __shfl_xor(vm, 4));
      vm = fmaxf(vm, __shfl_xor(vm, 8));              // row max across 16 lanes
      float mnew = fmaxf(mrow[r], vm);
      float alpha = __expf(mrow[r] - mnew);
      mrow[r] = mnew;
      float ps = 0.f;
#pragma unroll
      for (int t = 0; t < 4; t++) {
        float p = __expf(sval[t][r] - mnew);
        sval[t][r] = p; ps += p;
      }
      ps += __shfl_xor(ps, 1); ps += __shfl_xor(ps, 2);
      ps += __shfl_xor(ps, 4); ps += __shfl_xor(ps, 8);
      lrow[r] = lrow[r] * alpha + ps;
#pragma unroll
      for (int t = 0; t < 4; t++) oacc[t][r] *= alpha;
    }
#pragma unroll
    for (int t = 0; t < 4; t++)                       // P: C-layout -> LDS (bf16)
#pragma unroll
      for (int r = 0; r < 4; r++)
        Pt[wv][(quad * 4 + r) * 64 + t * 16 + l16] = (short)f2bits(sval[t][r]);

#pragma unroll
    for (int s = 0; s < 2; s++) {                     // O += P * V
      short8 pf = *(short8*)&Pt[wv][l16 * 64 + quad * 8 + s * 32];   // A-frag m=l16,k=key
#pragma unroll
      for (int t = 0; t < 4; t++) {
        short8 vf = *(short8*)&Vt[(t * 16 + l16) * 64 + quad * 8 + s * 32];  // B-frag n=hd
        oacc[t] = __builtin_amdgcn_mfma_f32_16x16x32_bf16(pf, vf, oacc[t], 0, 0, 0);
      }
    }
  }
#pragma unroll
  for (int r = 0; r < 4; r++) {                       // normalize + store bf16
    float inv = 1.0f / lrow[r];
    int row = b * Nc + qrow0 + wv * 16 + quad * 4 + r;
#pragma unroll
    for (int t = 0; t < 4; t++)
      Aout[(size_t)row * Dc + h * HDc + t * 16 + l16] = (short)f2bits(oacc[t][r] * inv);
  }
}

extern "C" void kernel_launch(void* const* d_in, const int* in_sizes, int n_in,
                              void* d_out, int out_size, void* d_ws, size_t ws_size,
                              hipStream_t stream) {
  const float* q    = (const float*)d_in[0];
  const void*  mask = d_in[1];
  const float* bias = (const float*)d_in[2];
  const float* Wq   = (const float*)d_in[3];
  const float* Wk   = (const float*)d_in[4];
  const float* Wv   = (const float*)d_in[5];
  const float* Wo   = (const float*)d_in[6];
  float* out = (float*)d_out;

  char* ws = (char*)d_ws;
  short* qb   = (short*)ws;  ws += (size_t)Mc * Dc * 2;        // q in bf16        (8 MB)
  short* Wqkv = (short*)ws;  ws += (size_t)QKVNc * Dc * 2;     // Wq|Wk|Wv bf16    (1.5 MB)
  short* Wob  = (short*)ws;  ws += (size_t)Dc * Dc * 2;        // Wo bf16          (0.5 MB)
  float* mf   = (float*)ws;  ws += (size_t)Bc * Nc * 4;        // additive mask    (32 KB)
  int*   mflag= (int*)ws;    ws += 256;                        // mask dtype flag
  short* QKV  = (short*)ws;  ws += (size_t)Mc * QKVNc * 2;     // projections      (24 MB)
  short* aout = (short*)ws;  ws += (size_t)Mc * Dc * 2;        // attn out bf16    (8 MB)

  auto cvt = [&](const float* s, short* d, int n) {
    int n4 = n >> 2;
    cvt_kernel<<<dim3((n4 + 255) / 256), dim3(256), 0, stream>>>(s, d, n4);
  };
  cvt(q, qb, Mc * Dc);
  cvt(Wq, Wqkv,               Dc * Dc);
  cvt(Wk, Wqkv + Dc * Dc,     Dc * Dc);
  cvt(Wv, Wqkv + 2 * Dc * Dc, Dc * Dc);
  cvt(Wo, Wob, Dc * Dc);
  detect_kernel<<<dim3(1), dim3(256), 0, stream>>>((const uchar4*)mask, mflag);
  mask_kernel<<<dim3((Bc * Nc + 255) / 256), dim3(256), 0, stream>>>(mask, mflag, mf, Bc * Nc);

  gemm_bt<false><<<dim3(QKVNc / 128, Mc / 128), dim3(256), 0, stream>>>(qb, Wqkv, (void*)QKV, Mc, QKVNc, Dc);
  attn_kernel<<<dim3(Bc * Hc * 32), dim3(256), 0, stream>>>(QKV, bias, mf, aout);
  gemm_bt<true><<<dim3(Dc / 128, Mc / 128), dim3(256), 0, stream>>>(aout, Wob, (void*)out, Mc, Dc, Dc);
}

// Round 3
// 309.555 us; speedup vs baseline: 1.1561x; 1.1561x over previous
//
#include <hip/hip_runtime.h>
#include <stdint.h>

// MultiHeadAttentionProj: B=4, N=2048, D=512, H=8, HD=64
// cvt(f32->bf16) -> GEMM QKV (Q pre-scaled by 1/8) -> flash attn (S^T form,
// no-max softmax, deferred row-sum) -> GEMM out. fp32 accumulation.

typedef __attribute__((ext_vector_type(8))) short short8;
typedef __attribute__((ext_vector_type(4))) short short4v;
typedef __attribute__((ext_vector_type(4))) float f32x4;

#define DEV static __device__ __forceinline__

constexpr int Bc = 4, Nc = 2048, Dc = 512, Hc = 8, HDc = 64;
constexpr int Mc = Bc * Nc;        // 8192 rows
constexpr int QKVNc = 3 * Dc;      // 1536

DEV unsigned short f2bits(float f) {   // f32 -> bf16 bits, RNE
  union { float f; unsigned u; } a; a.f = f;
  unsigned r = a.u + 0x7fffu + ((a.u >> 16) & 1u);
  return (unsigned short)(r >> 16);
}
DEV unsigned pack_bf16x2(float a, float b) {  // a->low16, b->high16 (RNE both)
  unsigned ua = __float_as_uint(a), ub = __float_as_uint(b);
  ua = ua + 0x7fffu + ((ua >> 16) & 1u);
  ub = ub + 0x7fffu + ((ub >> 16) & 1u);
  return __builtin_amdgcn_perm(ub, ua, 0x07060302);  // {ub[3],ub[2],ua[3],ua[2]}
}

__global__ void cvt_kernel(const float* __restrict__ src, short* __restrict__ dst, int n4) {
  int i = blockIdx.x * blockDim.x + threadIdx.x;
  if (i >= n4) return;
  float4 v = ((const float4*)src)[i];
  short4v o = { (short)f2bits(v.x), (short)f2bits(v.y), (short)f2bits(v.z), (short)f2bits(v.w) };
  ((short4v*)dst)[i] = o;
}

// mask may arrive as int32 (4B) or bool bytes (1B); detect on-device.
__global__ void detect_kernel(const uchar4* __restrict__ m, int* __restrict__ flag) {
  __shared__ int s;
  if (threadIdx.x == 0) s = 0;
  __syncthreads();
  int acc = 0;
  for (int i = threadIdx.x; i < (Bc * Nc) / 4; i += 256) {
    uchar4 v = m[i];
    acc |= (int)v.y | (int)v.z | (int)v.w;
  }
  if (acc) atomicOr(&s, 1);
  __syncthreads();
  if (threadIdx.x == 0) *flag = s;
}

__global__ void mask_kernel(const void* __restrict__ mask, const int* __restrict__ flag,
                            float* __restrict__ mf, int n) {
  int i = blockIdx.x * blockDim.x + threadIdx.x;
  if (i >= n) return;
  int isbyte = *flag;
  int v = isbyte ? (int)((const unsigned char*)mask)[i] : ((const int*)mask)[i];
  mf[i] = v ? -1e30f : 0.0f;
}

// C[M][N] = sum_k A[m][k]*Bm[n][k]. 128x128 tile, BK=64, LDS rows padded to 72
// shorts (144B) so b128 frag reads rotate 4 banks/row -> conflict-free.
// Columns < qcols get scaled by cscale (folds 1/sqrt(HD) into Q).
template<bool OUT_F32>
__global__ __launch_bounds__(256) void gemm_bt(const short* __restrict__ A,
                                               const short* __restrict__ Bm,
                                               void* __restrict__ Cv,
                                               int M, int N, int K,
                                               int qcols, float cscale) {
  __shared__ __align__(16) short At[128 * 72];
  __shared__ __align__(16) short Bt[128 * 72];
  const int tid = threadIdx.x, lane = tid & 63, wv = tid >> 6;
  const int quad = lane >> 4, l16 = lane & 15;
  const int mbase = blockIdx.y * 128, nbase = blockIdx.x * 128;
  const int wr = (wv >> 1) * 64, wc = (wv & 1) * 64;
  const float scale = (nbase < qcols) ? cscale : 1.0f;   // block-uniform
  f32x4 acc[4][4] = {};
  for (int k0 = 0; k0 < K; k0 += 64) {
    __syncthreads();
#pragma unroll
    for (int i = 0; i < 4; i++) {
      int flat = i * 256 + tid;                 // 1024 chunks of 16B, 8/row
      int row = flat >> 3, ch8 = (flat & 7) * 8;
      *(short8*)&At[row * 72 + ch8] = *(const short8*)&A[(size_t)(mbase + row) * K + k0 + ch8];
      *(short8*)&Bt[row * 72 + ch8] = *(const short8*)&Bm[(size_t)(nbase + row) * K + k0 + ch8];
    }
    __syncthreads();
#pragma unroll
    for (int s = 0; s < 2; s++) {
      short8 af[4], bf[4];
#pragma unroll
      for (int t = 0; t < 4; t++) {
        af[t] = *(short8*)&At[(wr + t * 16 + l16) * 72 + quad * 8 + s * 32];
        bf[t] = *(short8*)&Bt[(wc + t * 16 + l16) * 72 + quad * 8 + s * 32];
      }
#pragma unroll
      for (int mt = 0; mt < 4; mt++)
#pragma unroll
        for (int nt = 0; nt < 4; nt++)
          acc[mt][nt] = __builtin_amdgcn_mfma_f32_16x16x32_bf16(af[mt], bf[nt], acc[mt][nt], 0, 0, 0);
    }
  }
#pragma unroll
  for (int mt = 0; mt < 4; mt++)
#pragma unroll
    for (int nt = 0; nt < 4; nt++)
#pragma unroll
      for (int r = 0; r < 4; r++) {             // C/D: row=quad*4+r, col=l16
        int row = mbase + wr + mt * 16 + quad * 4 + r;
        int col = nbase + wc + nt * 16 + l16;
        float v = acc[mt][nt][r] * scale;
        if (OUT_F32) ((float*)Cv)[(size_t)row * N + col] = v;
        else         ((short*)Cv)[(size_t)row * N + col] = (short)f2bits(v);
      }
}

// Flash attention, S^T form. Block = (b,h,64 q-rows); 4 waves x 16 q-rows.
// S^T = K·Q^T: lane (l16,quad) holds S values for q=l16 only -> row-sum is
// lane-local (deferred cross-quad shfl at end); no max-subtraction (scores
// bounded, masked keys -> exp(-1e30)=0).
__global__ __launch_bounds__(256) void attn_kernel(const short* __restrict__ QKV,
                                                   const float* __restrict__ bias,
                                                   const float* __restrict__ maskf,
                                                   short* __restrict__ Aout) {
  __shared__ __align__(16) short Kt[64 * 72];        // [key][hd], padded
  __shared__ __align__(16) short Vt[64 * 72];        // [hd][key], padded
  __shared__ __align__(16) short Pt[4][16 * 72];     // per-wave P[q][key]
  __shared__ float lred[4][16];
  const int tid = threadIdx.x, lane = tid & 63, wv = tid >> 6;
  const int quad = lane >> 4, l16 = lane & 15;
  const int qt = blockIdx.x & 31, h = (blockIdx.x >> 5) & 7, b = (int)(blockIdx.x >> 8);
  const int qrow0 = qt * 64;
  const int qglob = qrow0 + wv * 16 + l16;           // this lane's q row
  const float* biasrow = bias + ((size_t)b * Nc + qglob) * Nc;
  const float* mfb = maskf + b * Nc;

  short8 qf[2];  // Q frag (pre-scaled by 1/8): [q=l16][k=quad*8+j (+32s)]
  {
    const short* qp = QKV + (size_t)(b * Nc + qglob) * QKVNc + h * HDc + quad * 8;
    qf[0] = *(const short8*)qp;
    qf[1] = *(const short8*)(qp + 32);
  }
  f32x4 oacc[4] = {};
  float lsum = 0.f;

  for (int kt = 0; kt < 32; kt++) {
    const int kb = kt * 64;
    __syncthreads();
#pragma unroll
    for (int i = 0; i < 2; i++) {                    // stage K: 64 keys x 64 hd
      int flat = i * 256 + tid;                      // 512 chunks, 8/row
      int row = flat >> 3, ch8 = (flat & 7) * 8;
      *(short8*)&Kt[row * 72 + ch8] =
          *(const short8*)&QKV[(size_t)(b * Nc + kb + row) * QKVNc + Dc + h * HDc + ch8];
    }
#pragma unroll
    for (int i = 0; i < 2; i++) {                    // stage V transposed [hd][key]
      int flat = i * 256 + tid;
      int hd0 = (flat >> 6) * 8, key = flat & 63;
      short8 v = *(const short8*)&QKV[(size_t)(b * Nc + kb + key) * QKVNc + 2 * Dc + h * HDc + hd0];
#pragma unroll
      for (int j = 0; j < 8; j++) Vt[(hd0 + j) * 72 + key] = v[j];
    }
    __syncthreads();

    f32x4 sacc[4] = {};                              // S^T[key=t*16+quad*4+r][q=l16]
#pragma unroll
    for (int s = 0; s < 2; s++)
#pragma unroll
      for (int t = 0; t < 4; t++) {                  // A = K frag (m=key), B = Q frag (n=q)
        short8 kf = *(short8*)&Kt[(t * 16 + l16) * 72 + quad * 8 + s * 32];
        sacc[t] = __builtin_amdgcn_mfma_f32_16x16x32_bf16(kf, qf[s], sacc[t], 0, 0, 0);
      }

#pragma unroll
    for (int t = 0; t < 4; t++) {
      int kc = kb + t * 16 + quad * 4;               // 4 consecutive keys (r=0..3)
      float4 bv = *(const float4*)&biasrow[kc];
      float4 mv = *(const float4*)&mfb[kc];
      float p0 = __expf(sacc[t][0] + mv.x + bv.x);
      float p1 = __expf(sacc[t][1] + mv.y + bv.y);
      float p2 = __expf(sacc[t][2] + mv.z + bv.z);
      float p3 = __expf(sacc[t][3] + mv.w + bv.w);
      lsum += (p0 + p1) + (p2 + p3);
      uint2 u = { pack_bf16x2(p0, p1), pack_bf16x2(p2, p3) };
      *(uint2*)&Pt[wv][l16 * 72 + t * 16 + quad * 4] = u;   // P[q=l16][key], b64
    }

#pragma unroll
    for (int s = 0; s < 2; s++) {                    // O += P·V (same-wave Pt)
      short8 pf = *(short8*)&Pt[wv][l16 * 72 + quad * 8 + s * 32];
#pragma unroll
      for (int t = 0; t < 4; t++) {
        short8 vf = *(short8*)&Vt[(t * 16 + l16) * 72 + quad * 8 + s * 32];
        oacc[t] = __builtin_amdgcn_mfma_f32_16x16x32_bf16(pf, vf, oacc[t], 0, 0, 0);
      }
    }
  }

  lsum += __shfl_xor(lsum, 16);                      // sum the 4 quads -> full l(q=l16)
  lsum += __shfl_xor(lsum, 32);
  if (quad == 0) lred[wv][l16] = lsum;               // same-wave produce/consume
#pragma unroll
  for (int r = 0; r < 4; r++) {                      // O C-layout: row q=quad*4+r, col hd
    float inv = 1.0f / lred[wv][quad * 4 + r];
    int row = b * Nc + qrow0 + wv * 16 + quad * 4 + r;
#pragma unroll
    for (int t = 0; t < 4; t++)
      Aout[(size_t)row * Dc + h * HDc + t * 16 + l16] = (short)f2bits(oacc[t][r] * inv);
  }
}

extern "C" void kernel_launch(void* const* d_in, const int* in_sizes, int n_in,
                              void* d_out, int out_size, void* d_ws, size_t ws_size,
                              hipStream_t stream) {
  const float* q    = (const float*)d_in[0];
  const void*  mask = d_in[1];
  const float* bias = (const float*)d_in[2];
  const float* Wq   = (const float*)d_in[3];
  const float* Wk   = (const float*)d_in[4];
  const float* Wv   = (const float*)d_in[5];
  const float* Wo   = (const float*)d_in[6];
  float* out = (float*)d_out;

  char* ws = (char*)d_ws;
  short* qb   = (short*)ws;  ws += (size_t)Mc * Dc * 2;
  short* Wqkv = (short*)ws;  ws += (size_t)QKVNc * Dc * 2;
  short* Wob  = (short*)ws;  ws += (size_t)Dc * Dc * 2;
  float* mf   = (float*)ws;  ws += (size_t)Bc * Nc * 4;
  int*   mflag= (int*)ws;    ws += 256;
  short* QKV  = (short*)ws;  ws += (size_t)Mc * QKVNc * 2;
  short* aout = (short*)ws;  ws += (size_t)Mc * Dc * 2;

  auto cvt = [&](const float* s, short* d, int n) {
    int n4 = n >> 2;
    cvt_kernel<<<dim3((n4 + 255) / 256), dim3(256), 0, stream>>>(s, d, n4);
  };
  cvt(q, qb, Mc * Dc);
  cvt(Wq, Wqkv,               Dc * Dc);
  cvt(Wk, Wqkv + Dc * Dc,     Dc * Dc);
  cvt(Wv, Wqkv + 2 * Dc * Dc, Dc * Dc);
  cvt(Wo, Wob, Dc * Dc);
  detect_kernel<<<dim3(1), dim3(256), 0, stream>>>((const uchar4*)mask, mflag);
  mask_kernel<<<dim3((Bc * Nc + 255) / 256), dim3(256), 0, stream>>>(mask, mflag, mf, Bc * Nc);

  // QKV projection; Q columns (<512) scaled by 1/sqrt(HD)=0.125
  gemm_bt<false><<<dim3(QKVNc / 128, Mc / 128), dim3(256), 0, stream>>>(
      qb, Wqkv, (void*)QKV, Mc, QKVNc, Dc, Dc, 0.125f);
  attn_kernel<<<dim3(Bc * Hc * 32), dim3(256), 0, stream>>>(QKV, bias, mf, aout);
  gemm_bt<true><<<dim3(Dc / 128, Mc / 128), dim3(256), 0, stream>>>(
      aout, Wob, (void*)out, Mc, Dc, Dc, 0, 1.0f);
}

// Round 4
// 270.057 us; speedup vs baseline: 1.3252x; 1.1463x over previous
//
#include <hip/hip_runtime.h>
#include <stdint.h>

// MultiHeadAttentionProj: B=4, N=2048, D=512, H=8, HD=64
// cvt(f32->bf16) -> GEMM QKV (Q pre-scaled 1/8, reg-prefetch pipeline) ->
// flash attn (S^T form, no-max softmax, reg-prefetch of K/V/bias, mask in LDS)
// -> GEMM out. fp32 accumulation.

typedef __attribute__((ext_vector_type(8))) short short8;
typedef __attribute__((ext_vector_type(4))) short short4v;
typedef __attribute__((ext_vector_type(4))) float f32x4;

#define DEV static __device__ __forceinline__

constexpr int Bc = 4, Nc = 2048, Dc = 512, Hc = 8, HDc = 64;
constexpr int Mc = Bc * Nc;        // 8192 rows
constexpr int QKVNc = 3 * Dc;      // 1536

DEV unsigned short f2bits(float f) {   // f32 -> bf16 bits, RNE
  union { float f; unsigned u; } a; a.f = f;
  unsigned r = a.u + 0x7fffu + ((a.u >> 16) & 1u);
  return (unsigned short)(r >> 16);
}
DEV unsigned pack_bf16x2(float a, float b) {  // a->low16, b->high16 (RNE)
  unsigned ua = __float_as_uint(a), ub = __float_as_uint(b);
  ua = ua + 0x7fffu + ((ua >> 16) & 1u);
  ub = ub + 0x7fffu + ((ub >> 16) & 1u);
  return __builtin_amdgcn_perm(ub, ua, 0x07060302);
}
DEV unsigned pack_shorts(short a, short b) {  // {a,b} -> u32
  return (unsigned)(unsigned short)a | ((unsigned)(unsigned short)b << 16);
}

__global__ void cvt_kernel(const float* __restrict__ src, short* __restrict__ dst, int n4) {
  int i = blockIdx.x * blockDim.x + threadIdx.x;
  if (i >= n4) return;
  float4 v = ((const float4*)src)[i];
  short4v o = { (short)f2bits(v.x), (short)f2bits(v.y), (short)f2bits(v.z), (short)f2bits(v.w) };
  ((short4v*)dst)[i] = o;
}

// mask may arrive as int32 (4B) or bool bytes (1B); detect on-device.
__global__ void detect_kernel(const uchar4* __restrict__ m, int* __restrict__ flag) {
  __shared__ int s;
  if (threadIdx.x == 0) s = 0;
  __syncthreads();
  int acc = 0;
  for (int i = threadIdx.x; i < (Bc * Nc) / 4; i += 256) {
    uchar4 v = m[i];
    acc |= (int)v.y | (int)v.z | (int)v.w;
  }
  if (acc) atomicOr(&s, 1);
  __syncthreads();
  if (threadIdx.x == 0) *flag = s;
}

__global__ void mask_kernel(const void* __restrict__ mask, const int* __restrict__ flag,
                            float* __restrict__ mf, int n) {
  int i = blockIdx.x * blockDim.x + threadIdx.x;
  if (i >= n) return;
  int isbyte = *flag;
  int v = isbyte ? (int)((const unsigned char*)mask)[i] : ((const int*)mask)[i];
  mf[i] = v ? -1e30f : 0.0f;
}

// C[M][N] = sum_k A[m][k]*Bm[n][k]. 128x128 tile, BK=64, rows padded to 72
// shorts; register-prefetch pipeline: loads for k0+64 in flight over MFMAs.
template<bool OUT_F32>
__global__ __launch_bounds__(256) void gemm_bt(const short* __restrict__ A,
                                               const short* __restrict__ Bm,
                                               void* __restrict__ Cv,
                                               int M, int N, int K,
                                               int qcols, float cscale) {
  __shared__ __align__(16) short At[128 * 72];
  __shared__ __align__(16) short Bt[128 * 72];
  const int tid = threadIdx.x, lane = tid & 63, wv = tid >> 6;
  const int quad = lane >> 4, l16 = lane & 15;
  const int mbase = blockIdx.y * 128, nbase = blockIdx.x * 128;
  const int wr = (wv >> 1) * 64, wc = (wv & 1) * 64;
  const float scale = (nbase < qcols) ? cscale : 1.0f;
  const int srow = tid >> 1, sch8 = (tid & 1) * 32;  // unused fallback mapping
  (void)srow; (void)sch8;
  f32x4 acc[4][4] = {};
  short8 apre[4], bpre[4];
#pragma unroll
  for (int i = 0; i < 4; i++) {                 // preload k0=0
    int flat = i * 256 + tid, row = flat >> 3, ch8 = (flat & 7) * 8;
    apre[i] = *(const short8*)&A[(size_t)(mbase + row) * K + ch8];
    bpre[i] = *(const short8*)&Bm[(size_t)(nbase + row) * K + ch8];
  }
  for (int k0 = 0; k0 < K; k0 += 64) {
    __syncthreads();
#pragma unroll
    for (int i = 0; i < 4; i++) {
      int flat = i * 256 + tid, row = flat >> 3, ch8 = (flat & 7) * 8;
      *(short8*)&At[row * 72 + ch8] = apre[i];
      *(short8*)&Bt[row * 72 + ch8] = bpre[i];
    }
    if (k0 + 64 < K) {
#pragma unroll
      for (int i = 0; i < 4; i++) {             // prefetch next tile
        int flat = i * 256 + tid, row = flat >> 3, ch8 = (flat & 7) * 8;
        apre[i] = *(const short8*)&A[(size_t)(mbase + row) * K + k0 + 64 + ch8];
        bpre[i] = *(const short8*)&Bm[(size_t)(nbase + row) * K + k0 + 64 + ch8];
      }
    }
    __syncthreads();
#pragma unroll
    for (int s = 0; s < 2; s++) {
      short8 af[4], bf[4];
#pragma unroll
      for (int t = 0; t < 4; t++) {
        af[t] = *(short8*)&At[(wr + t * 16 + l16) * 72 + quad * 8 + s * 32];
        bf[t] = *(short8*)&Bt[(wc + t * 16 + l16) * 72 + quad * 8 + s * 32];
      }
#pragma unroll
      for (int mt = 0; mt < 4; mt++)
#pragma unroll
        for (int nt = 0; nt < 4; nt++)
          acc[mt][nt] = __builtin_amdgcn_mfma_f32_16x16x32_bf16(af[mt], bf[nt], acc[mt][nt], 0, 0, 0);
    }
  }
#pragma unroll
  for (int mt = 0; mt < 4; mt++)
#pragma unroll
    for (int nt = 0; nt < 4; nt++)
#pragma unroll
      for (int r = 0; r < 4; r++) {             // C/D: row=quad*4+r, col=l16
        int row = mbase + wr + mt * 16 + quad * 4 + r;
        int col = nbase + wc + nt * 16 + l16;
        float v = acc[mt][nt][r] * scale;
        if (OUT_F32) ((float*)Cv)[(size_t)row * N + col] = v;
        else         ((short*)Cv)[(size_t)row * N + col] = (short)f2bits(v);
      }
}

// Flash attention, S^T form, software-pipelined.
// Block = (b,h,64 q-rows); 4 waves x 16 q-rows. Lane (l16,quad) holds S for
// q=l16 only -> lane-local row-sum, no max-subtraction.
__global__ __launch_bounds__(256) void attn_kernel(const short* __restrict__ QKV,
                                                   const float* __restrict__ bias,
                                                   const float* __restrict__ maskf,
                                                   short* __restrict__ Aout) {
  __shared__ __align__(16) short Kt[64 * 72];        // [key][hd]
  __shared__ __align__(16) short Vt[64 * 72];        // [hd][key]
  __shared__ __align__(16) short Pt[4][16 * 72];     // per-wave P[q][key]
  __shared__ __align__(16) float mlds[Nc];           // this batch's mask row
  __shared__ float lred[4][16];
  const int tid = threadIdx.x, lane = tid & 63, wv = tid >> 6;
  const int quad = lane >> 4, l16 = lane & 15;
  const int qt = blockIdx.x & 31, h = (blockIdx.x >> 5) & 7, b = (int)(blockIdx.x >> 8);
  const int qrow0 = qt * 64;
  const int qglob = qrow0 + wv * 16 + l16;
  const float* biasrow = bias + ((size_t)b * Nc + qglob) * Nc;
  const float* mfb = maskf + b * Nc;

  ((float4*)mlds)[tid]       = ((const float4*)mfb)[tid];        // 2048 floats
  ((float4*)mlds)[256 + tid] = ((const float4*)mfb)[256 + tid];

  short8 qf[2];  // Q frag (pre-scaled by 1/8): [q=l16][k=quad*8+j (+32s)]
  {
    const short* qp = QKV + (size_t)(b * Nc + qglob) * QKVNc + h * HDc + quad * 8;
    qf[0] = *(const short8*)qp;
    qf[1] = *(const short8*)(qp + 32);
  }

  const int vp = tid & 31, vg = tid >> 5;            // V staging: key-pair, hd-group
  const short* Kbase = QKV + Dc + h * HDc;
  const short* Vbase = QKV + 2 * Dc + h * HDc;

  short8 kpre[2], v0pre, v1pre;
  float4 bpre[4];
#pragma unroll
  for (int i = 0; i < 2; i++) {                      // preload K tile 0
    int flat = i * 256 + tid, row = flat >> 3, ch8 = (flat & 7) * 8;
    kpre[i] = *(const short8*)&Kbase[(size_t)(b * Nc + row) * QKVNc + ch8];
  }
  v0pre = *(const short8*)&Vbase[(size_t)(b * Nc + 2 * vp) * QKVNc + vg * 8];
  v1pre = *(const short8*)&Vbase[(size_t)(b * Nc + 2 * vp + 1) * QKVNc + vg * 8];
#pragma unroll
  for (int t = 0; t < 4; t++) bpre[t] = *(const float4*)&biasrow[t * 16 + quad * 4];

  f32x4 oacc[4] = {};
  float lsum = 0.f;

  for (int kt = 0; kt < 32; kt++) {
    const int kb = kt * 64;
    const int kbn = ((kt + 1) & 31) * 64;            // next tile (wraps, in-bounds)
    __syncthreads();                                 // prev iter LDS reads done
#pragma unroll
    for (int i = 0; i < 2; i++) {                    // K regs -> LDS
      int flat = i * 256 + tid, row = flat >> 3, ch8 = (flat & 7) * 8;
      *(short8*)&Kt[row * 72 + ch8] = kpre[i];
    }
#pragma unroll
    for (int j = 0; j < 8; j++)                      // V regs -> LDS transposed (b32)
      *(unsigned*)&Vt[(vg * 8 + j) * 72 + 2 * vp] = pack_shorts(v0pre[j], v1pre[j]);

    float4 bcur[4];
#pragma unroll
    for (int t = 0; t < 4; t++) bcur[t] = bpre[t];
#pragma unroll
    for (int i = 0; i < 2; i++) {                    // prefetch K tile kt+1
      int flat = i * 256 + tid, row = flat >> 3, ch8 = (flat & 7) * 8;
      kpre[i] = *(const short8*)&Kbase[(size_t)(b * Nc + kbn + row) * QKVNc + ch8];
    }
    v0pre = *(const short8*)&Vbase[(size_t)(b * Nc + kbn + 2 * vp) * QKVNc + vg * 8];
    v1pre = *(const short8*)&Vbase[(size_t)(b * Nc + kbn + 2 * vp + 1) * QKVNc + vg * 8];
#pragma unroll
    for (int t = 0; t < 4; t++) bpre[t] = *(const float4*)&biasrow[kbn + t * 16 + quad * 4];
    __syncthreads();                                 // LDS tile kt ready

    f32x4 sacc[4] = {};                              // S^T[key=t*16+quad*4+r][q=l16]
#pragma unroll
    for (int s = 0; s < 2; s++)
#pragma unroll
      for (int t = 0; t < 4; t++) {                  // A=K frag (m=key), B=Q frag (n=q)
        short8 kf = *(short8*)&Kt[(t * 16 + l16) * 72 + quad * 8 + s * 32];
        sacc[t] = __builtin_amdgcn_mfma_f32_16x16x32_bf16(kf, qf[s], sacc[t], 0, 0, 0);
      }

#pragma unroll
    for (int t = 0; t < 4; t++) {
      float4 mv = *(const float4*)&mlds[kb + t * 16 + quad * 4];
      float p0 = __expf(sacc[t][0] + mv.x + bcur[t].x);
      float p1 = __expf(sacc[t][1] + mv.y + bcur[t].y);
      float p2 = __expf(sacc[t][2] + mv.z + bcur[t].z);
      float p3 = __expf(sacc[t][3] + mv.w + bcur[t].w);
      lsum += (p0 + p1) + (p2 + p3);
      uint2 u = { pack_bf16x2(p0, p1), pack_bf16x2(p2, p3) };
      *(uint2*)&Pt[wv][l16 * 72 + t * 16 + quad * 4] = u;   // P[q=l16][key]
    }

#pragma unroll
    for (int s = 0; s < 2; s++) {                    // O += P·V (same-wave Pt)
      short8 pf = *(short8*)&Pt[wv][l16 * 72 + quad * 8 + s * 32];
#pragma unroll
      for (int t = 0; t < 4; t++) {
        short8 vf = *(short8*)&Vt[(t * 16 + l16) * 72 + quad * 8 + s * 32];
        oacc[t] = __builtin_amdgcn_mfma_f32_16x16x32_bf16(pf, vf, oacc[t], 0, 0, 0);
      }
    }
  }

  lsum += __shfl_xor(lsum, 16);                      // sum 4 quads -> l(q=l16)
  lsum += __shfl_xor(lsum, 32);
  if (quad == 0) lred[wv][l16] = lsum;               // same-wave produce/consume
#pragma unroll
  for (int r = 0; r < 4; r++) {                      // O: row q=quad*4+r, col hd=l16
    float inv = 1.0f / lred[wv][quad * 4 + r];
    int row = b * Nc + qrow0 + wv * 16 + quad * 4 + r;
#pragma unroll
    for (int t = 0; t < 4; t++)
      Aout[(size_t)row * Dc + h * HDc + t * 16 + l16] = (short)f2bits(oacc[t][r] * inv);
  }
}

extern "C" void kernel_launch(void* const* d_in, const int* in_sizes, int n_in,
                              void* d_out, int out_size, void* d_ws, size_t ws_size,
                              hipStream_t stream) {
  const float* q    = (const float*)d_in[0];
  const void*  mask = d_in[1];
  const float* bias = (const float*)d_in[2];
  const float* Wq   = (const float*)d_in[3];
  const float* Wk   = (const float*)d_in[4];
  const float* Wv   = (const float*)d_in[5];
  const float* Wo   = (const float*)d_in[6];
  float* out = (float*)d_out;

  char* ws = (char*)d_ws;
  short* qb   = (short*)ws;  ws += (size_t)Mc * Dc * 2;
  short* Wqkv = (short*)ws;  ws += (size_t)QKVNc * Dc * 2;
  short* Wob  = (short*)ws;  ws += (size_t)Dc * Dc * 2;
  float* mf   = (float*)ws;  ws += (size_t)Bc * Nc * 4;
  int*   mflag= (int*)ws;    ws += 256;
  short* QKV  = (short*)ws;  ws += (size_t)Mc * QKVNc * 2;
  short* aout = (short*)ws;  ws += (size_t)Mc * Dc * 2;

  auto cvt = [&](const float* s, short* d, int n) {
    int n4 = n >> 2;
    cvt_kernel<<<dim3((n4 + 255) / 256), dim3(256), 0, stream>>>(s, d, n4);
  };
  cvt(q, qb, Mc * Dc);
  cvt(Wq, Wqkv,               Dc * Dc);
  cvt(Wk, Wqkv + Dc * Dc,     Dc * Dc);
  cvt(Wv, Wqkv + 2 * Dc * Dc, Dc * Dc);
  cvt(Wo, Wob, Dc * Dc);
  detect_kernel<<<dim3(1), dim3(256), 0, stream>>>((const uchar4*)mask, mflag);
  mask_kernel<<<dim3((Bc * Nc + 255) / 256), dim3(256), 0, stream>>>(mask, mflag, mf, Bc * Nc);

  gemm_bt<false><<<dim3(QKVNc / 128, Mc / 128), dim3(256), 0, stream>>>(
      qb, Wqkv, (void*)QKV, Mc, QKVNc, Dc, Dc, 0.125f);
  attn_kernel<<<dim3(Bc * Hc * 32), dim3(256), 0, stream>>>(QKV, bias, mf, aout);
  gemm_bt<true><<<dim3(Dc / 128, Mc / 128), dim3(256), 0, stream>>>(
      aout, Wob, (void*)out, Mc, Dc, Dc, 0, 1.0f);
}

// Round 7
// 263.418 us; speedup vs baseline: 1.3586x; 1.0252x over previous
//
#include <hip/hip_runtime.h>
#include <stdint.h>

// MultiHeadAttentionProj: B=4, N=2048, D=512, H=8, HD=64
// cvtW -> maskprep -> GEMM QKV (A=f32 q, converted in staging; Q scaled 1/8)
// -> flash attn (BM=128, 8 waves, S^T form, no-max softmax, reg-prefetch)
// -> GEMM out. fp32 accumulation.

typedef __attribute__((ext_vector_type(8))) short short8;
typedef __attribute__((ext_vector_type(4))) short short4v;
typedef __attribute__((ext_vector_type(4))) float f32x4;

#define DEV static __device__ __forceinline__

constexpr int Bc = 4, Nc = 2048, Dc = 512, Hc = 8, HDc = 64;
constexpr int Mc = Bc * Nc;        // 8192 rows
constexpr int QKVNc = 3 * Dc;      // 1536

DEV unsigned short f2bits(float f) {   // f32 -> bf16 bits, RNE
  union { float f; unsigned u; } a; a.f = f;
  unsigned r = a.u + 0x7fffu + ((a.u >> 16) & 1u);
  return (unsigned short)(r >> 16);
}
DEV unsigned pack_bf16x2(float a, float b) {  // a->low16, b->high16 (RNE)
  unsigned ua = __float_as_uint(a), ub = __float_as_uint(b);
  ua = ua + 0x7fffu + ((ua >> 16) & 1u);
  ub = ub + 0x7fffu + ((ub >> 16) & 1u);
  return __builtin_amdgcn_perm(ub, ua, 0x07060302);
}
DEV unsigned pack_shorts(short a, short b) {
  return (unsigned)(unsigned short)a | ((unsigned)(unsigned short)b << 16);
}
DEV short8 cvt8(float4 a, float4 b) {   // 8 f32 -> short8 bf16
  union { short8 s; uint4 u; } r;
  r.u.x = pack_bf16x2(a.x, a.y); r.u.y = pack_bf16x2(a.z, a.w);
  r.u.z = pack_bf16x2(b.x, b.y); r.u.w = pack_bf16x2(b.z, b.w);
  return r.s;
}

// One launch converts Wq,Wk,Wv -> Wqkv (concat) and Wo -> Wob.
__global__ void cvtw_kernel(const float* __restrict__ Wq, const float* __restrict__ Wk,
                            const float* __restrict__ Wv, const float* __restrict__ Wo,
                            short* __restrict__ Wqkv, short* __restrict__ Wob) {
  int which = blockIdx.x >> 8;                       // 4 x 256 blocks
  int j = (blockIdx.x & 255) * 256 + threadIdx.x;    // float4 index < 65536
  const float* src = which == 0 ? Wq : which == 1 ? Wk : which == 2 ? Wv : Wo;
  short* dst = (which == 3) ? Wob : Wqkv + which * (Dc * Dc);
  float4 v = ((const float4*)src)[j];
  short4v o = { (short)f2bits(v.x), (short)f2bits(v.y), (short)f2bits(v.z), (short)f2bits(v.w) };
  ((short4v*)dst)[j] = o;
}

// Single block: detect mask dtype (int32 vs bool bytes), then convert to
// additive floats. int32 0/1 LE has bytes 1..3 of every word zero.
__global__ void maskprep_kernel(const void* __restrict__ mask, float* __restrict__ mf) {
  __shared__ int flag;
  if (threadIdx.x == 0) flag = 0;
  __syncthreads();
  const uchar4* m4 = (const uchar4*)mask;
  int acc = 0;
  for (int i = threadIdx.x; i < 2048; i += 1024) {
    uchar4 v = m4[i];
    acc |= (int)v.y | (int)v.z | (int)v.w;
  }
  if (acc) atomicOr(&flag, 1);
  __syncthreads();
  int isbyte = flag;
  for (int i = threadIdx.x; i < Bc * Nc; i += 1024) {
    int v = isbyte ? (int)((const unsigned char*)mask)[i] : ((const int*)mask)[i];
    mf[i] = v ? -1e30f : 0.0f;
  }
}

// C[M][N] = sum_k A[m][k]*Bm[n][k]. 128x128 tile, BK=64, rows padded to 72
// shorts; reg-prefetch pipeline. A_F32: A is f32, converted during staging.
template<bool A_F32, bool OUT_F32>
__global__ __launch_bounds__(256, 2) void gemm_bt(const void* __restrict__ Av,
                                                  const short* __restrict__ Bm,
                                                  void* __restrict__ Cv,
                                                  int M, int N, int K,
                                                  int qcols, float cscale) {
  __shared__ __align__(16) short At[128 * 72];
  __shared__ __align__(16) short Bt[128 * 72];
  const int tid = threadIdx.x, lane = tid & 63, wv = tid >> 6;
  const int quad = lane >> 4, l16 = lane & 15;
  const int mbase = blockIdx.y * 128, nbase = blockIdx.x * 128;
  const int wr = (wv >> 1) * 64, wc = (wv & 1) * 64;
  const float scale = (nbase < qcols) ? cscale : 1.0f;
  f32x4 acc[4][4] = {};
  float4 apf[4][2]; short8 aph[4], bpre[4];
#pragma unroll
  for (int i = 0; i < 4; i++) {                 // preload k0=0
    int flat = i * 256 + tid, row = flat >> 3, ch8 = (flat & 7) * 8;
    if (A_F32) {
      const float* Af = (const float*)Av;
      apf[i][0] = *(const float4*)&Af[(size_t)(mbase + row) * K + ch8];
      apf[i][1] = *(const float4*)&Af[(size_t)(mbase + row) * K + ch8 + 4];
    } else {
      aph[i] = *(const short8*)&((const short*)Av)[(size_t)(mbase + row) * K + ch8];
    }
    bpre[i] = *(const short8*)&Bm[(size_t)(nbase + row) * K + ch8];
  }
  for (int k0 = 0; k0 < K; k0 += 64) {
    __syncthreads();
#pragma unroll
    for (int i = 0; i < 4; i++) {
      int flat = i * 256 + tid, row = flat >> 3, ch8 = (flat & 7) * 8;
      *(short8*)&At[row * 72 + ch8] = A_F32 ? cvt8(apf[i][0], apf[i][1]) : aph[i];
      *(short8*)&Bt[row * 72 + ch8] = bpre[i];
    }
    if (k0 + 64 < K) {
#pragma unroll
      for (int i = 0; i < 4; i++) {             // prefetch next tile
        int flat = i * 256 + tid, row = flat >> 3, ch8 = (flat & 7) * 8;
        if (A_F32) {
          const float* Af = (const float*)Av;
          apf[i][0] = *(const float4*)&Af[(size_t)(mbase + row) * K + k0 + 64 + ch8];
          apf[i][1] = *(const float4*)&Af[(size_t)(mbase + row) * K + k0 + 64 + ch8 + 4];
        } else {
          aph[i] = *(const short8*)&((const short*)Av)[(size_t)(mbase + row) * K + k0 + 64 + ch8];
        }
        bpre[i] = *(const short8*)&Bm[(size_t)(nbase + row) * K + k0 + 64 + ch8];
      }
    }
    __syncthreads();
#pragma unroll
    for (int s = 0; s < 2; s++) {
      short8 af[4], bf[4];
#pragma unroll
      for (int t = 0; t < 4; t++) {
        af[t] = *(short8*)&At[(wr + t * 16 + l16) * 72 + quad * 8 + s * 32];
        bf[t] = *(short8*)&Bt[(wc + t * 16 + l16) * 72 + quad * 8 + s * 32];
      }
#pragma unroll
      for (int mt = 0; mt < 4; mt++)
#pragma unroll
        for (int nt = 0; nt < 4; nt++)
          acc[mt][nt] = __builtin_amdgcn_mfma_f32_16x16x32_bf16(af[mt], bf[nt], acc[mt][nt], 0, 0, 0);
    }
  }
#pragma unroll
  for (int mt = 0; mt < 4; mt++)
#pragma unroll
    for (int nt = 0; nt < 4; nt++)
#pragma unroll
      for (int r = 0; r < 4; r++) {             // C/D: row=quad*4+r, col=l16
        int row = mbase + wr + mt * 16 + quad * 4 + r;
        int col = nbase + wc + nt * 16 + l16;
        float v = acc[mt][nt][r] * scale;
        if (OUT_F32) ((float*)Cv)[(size_t)row * N + col] = v;
        else         ((short*)Cv)[(size_t)row * N + col] = (short)f2bits(v);
      }
}

// Flash attention, S^T form, BM=128 q-rows, 512 threads (8 waves x 16 q-rows),
// 64-key tiles, register-prefetch of K/V/bias, mask in LDS.
__global__ __launch_bounds__(512, 3) void attn_kernel(const short* __restrict__ QKV,
                                                      const float* __restrict__ bias,
                                                      const float* __restrict__ maskf,
                                                      short* __restrict__ Aout) {
  __shared__ __align__(16) short Kt[64 * 72];        // [key][hd]
  __shared__ __align__(16) short Vt[64 * 72];        // [hd][key]
  __shared__ __align__(16) short Pt[8][16 * 72];     // per-wave P[q][key]
  __shared__ __align__(16) float mlds[Nc];
  __shared__ float lred[8][16];
  const int tid = threadIdx.x, lane = tid & 63, wv = tid >> 6;
  const int quad = lane >> 4, l16 = lane & 15;
  const int qt = blockIdx.x & 15, h = (blockIdx.x >> 4) & 7, b = (int)(blockIdx.x >> 7);
  const int qrow0 = qt * 128;
  const int qglob = qrow0 + wv * 16 + l16;
  const float* biasrow = bias + ((size_t)b * Nc + qglob) * Nc;
  const float* mfb = maskf + b * Nc;

  ((float4*)mlds)[tid] = ((const float4*)mfb)[tid];  // 512 float4 = 2048 floats

  short8 qf[2];  // Q frag (pre-scaled 1/8): [q=l16][k=quad*8+j (+32s)]
  {
    const short* qp = QKV + (size_t)(b * Nc + qglob) * QKVNc + h * HDc + quad * 8;
    qf[0] = *(const short8*)qp;
    qf[1] = *(const short8*)(qp + 32);
  }

  const int vp = tid & 31, vq = tid >> 5;            // key-pair 0..31, hd-quad 0..15
  const int krow = tid >> 3, kch = (tid & 7) * 8;    // K staging: 512 chunks, 1/thread
  const short* Kbase = QKV + Dc + h * HDc;
  const short* Vbase = QKV + 2 * Dc + h * HDc;

  short8 kpre; short4v v0pre, v1pre; float4 bpre[4];
  kpre  = *(const short8*)&Kbase[(size_t)(b * Nc + krow) * QKVNc + kch];
  v0pre = *(const short4v*)&Vbase[(size_t)(b * Nc + 2 * vp) * QKVNc + 4 * vq];
  v1pre = *(const short4v*)&Vbase[(size_t)(b * Nc + 2 * vp + 1) * QKVNc + 4 * vq];
#pragma unroll
  for (int t = 0; t < 4; t++) bpre[t] = *(const float4*)&biasrow[t * 16 + quad * 4];

  f32x4 oacc[4] = {};
  float lsum = 0.f;

  for (int kt = 0; kt < 32; kt++) {
    const int kb = kt * 64;
    const int kbn = ((kt + 1) & 31) * 64;            // next tile (wraps, in-bounds)
    __syncthreads();                                 // prev iter LDS reads done
    *(short8*)&Kt[krow * 72 + kch] = kpre;           // K regs -> LDS
#pragma unroll
    for (int j = 0; j < 4; j++)                      // V regs -> LDS transposed (b32)
      *(unsigned*)&Vt[(4 * vq + j) * 72 + 2 * vp] = pack_shorts(v0pre[j], v1pre[j]);

    float4 bcur[4];
#pragma unroll
    for (int t = 0; t < 4; t++) bcur[t] = bpre[t];
    kpre  = *(const short8*)&Kbase[(size_t)(b * Nc + kbn + krow) * QKVNc + kch];
    v0pre = *(const short4v*)&Vbase[(size_t)(b * Nc + kbn + 2 * vp) * QKVNc + 4 * vq];
    v1pre = *(const short4v*)&Vbase[(size_t)(b * Nc + kbn + 2 * vp + 1) * QKVNc + 4 * vq];
#pragma unroll
    for (int t = 0; t < 4; t++) bpre[t] = *(const float4*)&biasrow[kbn + t * 16 + quad * 4];
    __syncthreads();                                 // LDS tile kt ready

    f32x4 sacc[4] = {};                              // S^T[key=t*16+quad*4+r][q=l16]
#pragma unroll
    for (int s = 0; s < 2; s++)
#pragma unroll
      for (int t = 0; t < 4; t++) {                  // A=K frag (m=key), B=Q frag (n=q)
        short8 kf = *(short8*)&Kt[(t * 16 + l16) * 72 + quad * 8 + s * 32];
        sacc[t] = __builtin_amdgcn_mfma_f32_16x16x32_bf16(kf, qf[s], sacc[t], 0, 0, 0);
      }

#pragma unroll
    for (int t = 0; t < 4; t++) {
      float4 mv = *(const float4*)&mlds[kb + t * 16 + quad * 4];
      float p0 = __expf(sacc[t][0] + mv.x + bcur[t].x);
      float p1 = __expf(sacc[t][1] + mv.y + bcur[t].y);
      float p2 = __expf(sacc[t][2] + mv.z + bcur[t].z);
      float p3 = __expf(sacc[t][3] + mv.w + bcur[t].w);
      lsum += (p0 + p1) + (p2 + p3);
      uint2 u = { pack_bf16x2(p0, p1), pack_bf16x2(p2, p3) };
      *(uint2*)&Pt[wv][l16 * 72 + t * 16 + quad * 4] = u;   // P[q=l16][key]
    }

#pragma unroll
    for (int s = 0; s < 2; s++) {                    // O += P·V (same-wave Pt)
      short8 pf = *(short8*)&Pt[wv][l16 * 72 + quad * 8 + s * 32];
#pragma unroll
      for (int t = 0; t < 4; t++) {
        short8 vf = *(short8*)&Vt[(t * 16 + l16) * 72 + quad * 8 + s * 32];
        oacc[t] = __builtin_amdgcn_mfma_f32_16x16x32_bf16(pf, vf, oacc[t], 0, 0, 0);
      }
    }
  }

  lsum += __shfl_xor(lsum, 16);                      // sum 4 quads -> l(q=l16)
  lsum += __shfl_xor(lsum, 32);
  if (quad == 0) lred[wv][l16] = lsum;               // same-wave produce/consume
#pragma unroll
  for (int r = 0; r < 4; r++) {                      // O: row q=quad*4+r, col hd=l16
    float inv = 1.0f / lred[wv][quad * 4 + r];
    int row = b * Nc + qrow0 + wv * 16 + quad * 4 + r;
#pragma unroll
    for (int t = 0; t < 4; t++)
      Aout[(size_t)row * Dc + h * HDc + t * 16 + l16] = (short)f2bits(oacc[t][r] * inv);
  }
}

extern "C" void kernel_launch(void* const* d_in, const int* in_sizes, int n_in,
                              void* d_out, int out_size, void* d_ws, size_t ws_size,
                              hipStream_t stream) {
  const float* q    = (const float*)d_in[0];
  const void*  mask = d_in[1];
  const float* bias = (const float*)d_in[2];
  const float* Wq   = (const float*)d_in[3];
  const float* Wk   = (const float*)d_in[4];
  const float* Wv   = (const float*)d_in[5];
  const float* Wo   = (const float*)d_in[6];
  float* out = (float*)d_out;

  char* ws = (char*)d_ws;
  short* Wqkv = (short*)ws;  ws += (size_t)QKVNc * Dc * 2;
  short* Wob  = (short*)ws;  ws += (size_t)Dc * Dc * 2;
  float* mf   = (float*)ws;  ws += (size_t)Bc * Nc * 4;
  short* QKV  = (short*)ws;  ws += (size_t)Mc * QKVNc * 2;
  short* aout = (short*)ws;  ws += (size_t)Mc * Dc * 2;

  cvtw_kernel<<<dim3(1024), dim3(256), 0, stream>>>(Wq, Wk, Wv, Wo, Wqkv, Wob);
  maskprep_kernel<<<dim3(1), dim3(1024), 0, stream>>>(mask, mf);

  gemm_bt<true, false><<<dim3(QKVNc / 128, Mc / 128), dim3(256), 0, stream>>>(
      (const void*)q, Wqkv, (void*)QKV, Mc, QKVNc, Dc, Dc, 0.125f);
  attn_kernel<<<dim3(Bc * Hc * 16), dim3(512), 0, stream>>>(QKV, bias, mf, aout);
  gemm_bt<false, true><<<dim3(Dc / 128, Mc / 128), dim3(256), 0, stream>>>(
      (const void*)aout, Wob, (void*)out, Mc, Dc, Dc, 0, 1.0f);
}